// Round 14
// baseline (128.532 us; speedup 1.0000x reference)
//
#include <hip/hip_runtime.h>
#include <hip/hip_bf16.h>
#include <stdint.h>

typedef __attribute__((ext_vector_type(8))) short short8;
typedef __attribute__((ext_vector_type(4))) float float4_t;

#define DDIM 128
#define SORTN 256

__device__ inline unsigned short f32_to_bf16_rne(float f) {
    uint32_t u = __float_as_uint(f);
    return (unsigned short)((u + 0x7FFFu + ((u >> 16) & 1u)) >> 16);
}
__device__ inline float bf16_to_f32(unsigned short h) {
    return __uint_as_float(((uint32_t)h) << 16);
}
__device__ inline int ks_of(const int* seq_lens, int n_seq, int t) {
    int off = 0, r = 0;
    for (int i = 0; i < n_seq; ++i) {
        int nx = off + seq_lens[i];
        if (t < nx) { r = off; break; }
        off = nx;
    }
    return r;
}

// wave64 sum via DPP (VALU pipe). Result uniform.
__device__ inline int wave_reduce_add_dpp(int x) {
    x += __builtin_amdgcn_update_dpp(0, x, 0x111, 0xF, 0xF, true); // row_shr:1
    x += __builtin_amdgcn_update_dpp(0, x, 0x112, 0xF, 0xF, true); // row_shr:2
    x += __builtin_amdgcn_update_dpp(0, x, 0x114, 0xF, 0xF, true); // row_shr:4
    x += __builtin_amdgcn_update_dpp(0, x, 0x118, 0xF, 0xF, true); // row_shr:8
    x += __builtin_amdgcn_update_dpp(0, x, 0x142, 0xA, 0xF, true); // row_bcast:15
    x += __builtin_amdgcn_update_dpp(0, x, 0x143, 0xC, 0xF, true); // row_bcast:31
    return __builtin_amdgcn_readlane(x, 63);
}

// ---- pass 1: rotate k rows ----
__global__ __launch_bounds__(256) void rotate_k_kernel(
        const unsigned short* __restrict__ k, unsigned short* __restrict__ kr, int T) {
    int row = blockIdx.x * 16 + (threadIdx.x >> 4);
    if (row >= T) return;
    int l16 = threadIdx.x & 15;
    short8 in = *(const short8*)(k + (size_t)row * DDIM + 8 * l16);
    float f[8];
    #pragma unroll
    for (int j = 0; j < 8; ++j) f[j] = bf16_to_f32((unsigned short)in[j]);
    #pragma unroll
    for (int b = 1; b <= 4; b <<= 1)
        #pragma unroll
        for (int j = 0; j < 8; ++j)
            if (!(j & b)) { float a = f[j], c = f[j | b]; f[j] = a + c; f[j | b] = a - c; }
    #pragma unroll
    for (int m = 1; m <= 8; m <<= 1) {
        bool hi = (l16 & m) != 0;
        #pragma unroll
        for (int j = 0; j < 8; ++j) {
            float o = __shfl_xor(f[j], m, 64);
            f[j] = hi ? (o - f[j]) : (f[j] + o);
        }
    }
    const float sc = 0.08838834764831845f;
    short8 out;
    #pragma unroll
    for (int j = 0; j < 8; ++j) out[j] = (short)f32_to_bf16_rne(f[j] * sc);
    *(short8*)(kr + (size_t)row * DDIM + 8 * l16) = out;
}

// ---- per-wave: score all kv for token t, exact top-K, sorted emit ----
template <int NCHT>
__device__ __forceinline__ void wave_token_work(
        int t, int ks, int n, int T, int H, int K,
        const unsigned short* __restrict__ q,
        const unsigned short* __restrict__ kr,
        const float* __restrict__ w,
        volatile float* scratch64,            // wave-private 64 floats in LDS
        unsigned long long* candw,            // wave-private 256 u64 in LDS
        float* __restrict__ out_vals, float* __restrict__ out_idx,
        int lane, int col, int kgrp) {
    // ---- rotate q[t] in registers -> afrag (verified layout) ----
    float f[4][8];
    const unsigned short* qrow = q + ((size_t)t * H + col) * DDIM + kgrp * 8;
    #pragma unroll
    for (int kk = 0; kk < 4; ++kk) {
        short8 v = *(const short8*)(qrow + kk * 32);
        #pragma unroll
        for (int j = 0; j < 8; ++j) f[kk][j] = bf16_to_f32((unsigned short)v[j]);
    }
    #pragma unroll
    for (int b = 1; b <= 4; b <<= 1)
        #pragma unroll
        for (int kk = 0; kk < 4; ++kk)
            #pragma unroll
            for (int j = 0; j < 8; ++j)
                if (!(j & b)) { float a = f[kk][j], c = f[kk][j | b];
                                f[kk][j] = a + c; f[kk][j | b] = a - c; }
    #pragma unroll
    for (int kk = 0; kk < 4; ++kk)
        #pragma unroll
        for (int j = 0; j < 8; ++j) {
            float o = __shfl_xor(f[kk][j], 16, 64);
            f[kk][j] = (kgrp & 1) ? (o - f[kk][j]) : (f[kk][j] + o);
        }
    #pragma unroll
    for (int kk = 0; kk < 4; ++kk)
        #pragma unroll
        for (int j = 0; j < 8; ++j) {
            float o = __shfl_xor(f[kk][j], 32, 64);
            f[kk][j] = (kgrp & 2) ? (o - f[kk][j]) : (f[kk][j] + o);
        }
    #pragma unroll
    for (int j = 0; j < 8; ++j) {
        { float a = f[0][j], c = f[1][j]; f[0][j] = a + c; f[1][j] = a - c; }
        { float a = f[2][j], c = f[3][j]; f[2][j] = a + c; f[3][j] = a - c; }
        { float a = f[0][j], c = f[2][j]; f[0][j] = a + c; f[2][j] = a - c; }
        { float a = f[1][j], c = f[3][j]; f[1][j] = a + c; f[3][j] = a - c; }
    }
    short8 afrag[4];
    const float scl = 0.08838834764831845f;
    #pragma unroll
    for (int kk = 0; kk < 4; ++kk)
        #pragma unroll
        for (int j = 0; j < 8; ++j)
            afrag[kk][j] = (short)f32_to_bf16_rne(f[kk][j] * scl);

    float w4[4];
    #pragma unroll
    for (int r = 0; r < 4; ++r) w4[r] = w[(size_t)t * H + kgrp * 4 + r];

    // ---- score loop: 64 rows per chunk, no barriers, scores -> registers ----
    const int nchunk = (n + 63) >> 6;
    uint32_t ukey[NCHT];
    #pragma unroll
    for (int c = 0; c < NCHT; ++c) {
        if (c < nchunk) {
            const int s0 = ks + c * 64;
            #pragma unroll
            for (int j = 0; j < 4; ++j) {
                int sa = s0 + 16 * j + col;
                if (sa > T - 1) sa = T - 1;     // clamp; masked via i<n below
                const short8* kb = (const short8*)(kr + (size_t)sa * DDIM + kgrp * 8);
                float4_t acc = {0.f, 0.f, 0.f, 0.f};
                acc = __builtin_amdgcn_mfma_f32_16x16x32_bf16(afrag[0], kb[0],  acc, 0, 0, 0);
                acc = __builtin_amdgcn_mfma_f32_16x16x32_bf16(afrag[1], kb[4],  acc, 0, 0, 0);
                acc = __builtin_amdgcn_mfma_f32_16x16x32_bf16(afrag[2], kb[8],  acc, 0, 0, 0);
                acc = __builtin_amdgcn_mfma_f32_16x16x32_bf16(afrag[3], kb[12], acc, 0, 0, 0);
                float p = 0.f;
                #pragma unroll
                for (int r = 0; r < 4; ++r) {
                    float v = acc[r];
                    v = v > 0.f ? v : 0.f;
                    p += w4[r] * v;
                }
                p += __shfl_xor(p, 16, 64);
                p += __shfl_xor(p, 32, 64);
                if (lane < 16) scratch64[16 * j + lane] = p;  // wave-private LDS
            }
            float sv = scratch64[lane];                        // same-wave DS order
            ukey[c] = (c * 64 + lane < n) ? __float_as_uint(sv) : 0u;
        } else ukey[c] = 0u;
    }

    // ---- exact K-th via DPP binary search (verified) ----
    const int Keff = (n < K) ? n : K;
    uint32_t ustar = 0;
    int ttake = K;
    if (n > K) {
        uint32_t lo = 0, hi = 0x80000000u;
        for (int it = 0; it < 31; ++it) {
            uint32_t mid = (lo + hi) >> 1;
            int lc = 0;
            #pragma unroll
            for (int c = 0; c < NCHT; ++c)
                if (c < nchunk) lc += (ukey[c] >= mid) ? 1 : 0;
            int total = wave_reduce_add_dpp(lc);
            if (total >= K) lo = mid; else hi = mid;
        }
        ustar = lo;
        int lg = 0;
        #pragma unroll
        for (int c = 0; c < NCHT; ++c)
            if (c < nchunk) lg += (ukey[c] > ustar) ? 1 : 0;
        ttake = K - wave_reduce_add_dpp(lg);
    }

    // ---- gather exactly Keff keys (ties ascending index) ----
    {
        const unsigned long long ltm = (1ull << lane) - 1ull;
        int base = 0, tieBase = 0;
        const bool selAll = (n <= K);
        #pragma unroll
        for (int c = 0; c < NCHT; ++c) {
            if (c < nchunk) {
                int i = c * 64 + lane;
                bool inb = (i < n);
                uint32_t u = ukey[c];
                bool isGt  = inb && (selAll || u > ustar);
                bool isTie = inb && !selAll && (u == ustar);
                unsigned long long mt = __ballot(isTie);
                int tr = tieBase + (int)__popcll(mt & ltm);
                bool take = isGt || (isTie && tr < ttake);
                unsigned long long mk = __ballot(take);
                if (take) {
                    int pos = base + (int)__popcll(mk & ltm);
                    int s = ks + i;
                    if (pos < SORTN)
                        candw[pos] = ((((unsigned long long)u << 11) |
                                       (unsigned long long)(T - 1 - s)) + 1ull);
                }
                base    += (int)__popcll(mk);
                tieBase += (int)__popcll(mt);
            }
        }
        for (int i = Keff + lane; i < SORTN; i += 64) candw[i] = 0ull;
    }

    // ---- register bitonic sort of 256 keys, descending (verified) ----
    unsigned long long kreg[4];
    #pragma unroll
    for (int r = 0; r < 4; ++r) kreg[r] = candw[4 * lane + r];

    #define CX(a, b, dsc) { unsigned long long _mx = (a) > (b) ? (a) : (b); \
                            unsigned long long _mn = (a) > (b) ? (b) : (a); \
                            (a) = (dsc) ? _mx : _mn; (b) = (dsc) ? _mn : _mx; }
    #pragma unroll
    for (int size = 2; size <= SORTN; size <<= 1) {
        #pragma unroll
        for (int stride = SORTN >> 1; stride >= 4; stride >>= 1) {
            if (stride > (size >> 1)) continue;
            int lmask = stride >> 2;
            #pragma unroll
            for (int r = 0; r < 4; ++r) {
                int e = 4 * lane + r;
                unsigned long long other = __shfl_xor(kreg[r], lmask, 64);
                bool desc = ((e & size) == 0);
                bool iAmLow = ((e & stride) == 0);
                bool keepMax = (iAmLow == desc);
                kreg[r] = keepMax ? (kreg[r] > other ? kreg[r] : other)
                                  : (kreg[r] < other ? kreg[r] : other);
            }
        }
        if (size >= 4) {
            bool d = (((4 * lane) & size) == 0);
            CX(kreg[0], kreg[2], d);
            CX(kreg[1], kreg[3], d);
            CX(kreg[0], kreg[1], d);
            CX(kreg[2], kreg[3], d);
        } else {
            CX(kreg[0], kreg[1], true);
            CX(kreg[2], kreg[3], false);
        }
    }
    #undef CX

    // ---- emit ----
    if (4 * lane < K) {
        float4_t v4, i4;
        #pragma unroll
        for (int r = 0; r < 4; ++r) {
            int e = 4 * lane + r;
            unsigned long long key = kreg[r];
            float v; int idx;
            if (key != 0ull) {
                unsigned long long km1 = key - 1ull;
                v = __uint_as_float((uint32_t)(km1 >> 11));
                idx = T - 1 - (int)(km1 & 0x7FFull);
            } else {
                int pidx = e - Keff;
                idx = (pidx < ks) ? pidx : ((t + 1) + (pidx - ks));
                v = -1e30f;
            }
            v4[r] = v; i4[r] = (float)idx;
        }
        *(float4_t*)(out_vals + (size_t)t * K + 4 * lane) = v4;
        *(float4_t*)(out_idx  + (size_t)t * K + 4 * lane) = i4;
    }
}

// ---- pass 2: barrier-free fused kernel; one wave per token ----
__global__ __launch_bounds__(256, 2) void fused2_kernel(
        const unsigned short* __restrict__ q,
        const unsigned short* __restrict__ kr,
        const float* __restrict__ w,
        const int* __restrict__ seq_lens, int n_seq,
        float* __restrict__ out_vals, float* __restrict__ out_idx,
        int T, int H, int K, int NB) {
    __shared__ float scratch[4][64];                 // 1 KB, wave-private rows
    __shared__ unsigned long long cand[4][SORTN];    // 8 KB, wave-private rows

    const int wv = threadIdx.x >> 6, lane = threadIdx.x & 63;
    const int col = lane & 15, kgrp = lane >> 4;
    const int t = (int)blockIdx.x + NB * wv;         // depth-mixed per block & CU
    if (t >= T) return;
    const int ks = ks_of(seq_lens, n_seq, t);
    const int n  = t + 1 - ks;

    if (n <= 64 * 16)
        wave_token_work<16>(t, ks, n, T, H, K, q, kr, w,
                            scratch[wv], cand[wv], out_vals, out_idx, lane, col, kgrp);
    else
        wave_token_work<32>(t, ks, n, T, H, K, q, kr, w,
                            scratch[wv], cand[wv], out_vals, out_idx, lane, col, kgrp);
}

extern "C" void kernel_launch(void* const* d_in, const int* in_sizes, int n_in,
                              void* d_out, int out_size, void* d_ws, size_t ws_size,
                              hipStream_t stream) {
    const unsigned short* q = (const unsigned short*)d_in[0];
    const unsigned short* k = (const unsigned short*)d_in[1];
    const float* w          = (const float*)d_in[2];
    const int* seq_lens     = (const int*)d_in[3];
    const int n_seq = in_sizes[3];
    const int T = in_sizes[1] / DDIM;
    const int H = in_sizes[2] / T;
    const int K = out_size / (2 * T);

    unsigned short* kr = (unsigned short*)d_ws;   // [T,128] rotated k (512 KB)
    float* out_vals = (float*)d_out;
    float* out_idx  = out_vals + (size_t)T * K;

    rotate_k_kernel<<<dim3((T + 15) / 16), dim3(256), 0, stream>>>(k, kr, T);
    const int NB = (T + 3) / 4;                   // blocks; 4 waves (tokens) each
    fused2_kernel<<<dim3(NB), dim3(256), 0, stream>>>(
        q, kr, w, seq_lens, n_seq, out_vals, out_idx, T, H, K, NB);
}

// Round 15
// 106.587 us; speedup vs baseline: 1.2059x; 1.2059x over previous
//
#include <hip/hip_runtime.h>
#include <hip/hip_bf16.h>
#include <stdint.h>

typedef __attribute__((ext_vector_type(8))) short short8;
typedef __attribute__((ext_vector_type(4))) float float4_t;

#define DDIM 128
#define SORTN 256
#define LROW 136     // LDS B row pitch in shorts (272 B)
#define SCAP 1096    // per-token score row (floats); 1096%32=8 keeps writes <=2-way
#define NCHT 17      // selection chunks of 64 (covers n <= 1088)

__device__ inline unsigned short f32_to_bf16_rne(float f) {
    uint32_t u = __float_as_uint(f);
    return (unsigned short)((u + 0x7FFFu + ((u >> 16) & 1u)) >> 16);
}
__device__ inline float bf16_to_f32(unsigned short h) {
    return __uint_as_float(((uint32_t)h) << 16);
}
__device__ inline int ks_of(const int* seq_lens, int n_seq, int t) {
    int off = 0, r = 0;
    for (int i = 0; i < n_seq; ++i) {
        int nx = off + seq_lens[i];
        if (t < nx) { r = off; break; }
        off = nx;
    }
    return r;
}

// wave64 sum via DPP (VALU pipe; keeps the serial search off the DS pipe).
__device__ inline int wave_reduce_add_dpp(int x) {
    x += __builtin_amdgcn_update_dpp(0, x, 0x111, 0xF, 0xF, true); // row_shr:1
    x += __builtin_amdgcn_update_dpp(0, x, 0x112, 0xF, 0xF, true); // row_shr:2
    x += __builtin_amdgcn_update_dpp(0, x, 0x114, 0xF, 0xF, true); // row_shr:4
    x += __builtin_amdgcn_update_dpp(0, x, 0x118, 0xF, 0xF, true); // row_shr:8
    x += __builtin_amdgcn_update_dpp(0, x, 0x142, 0xA, 0xF, true); // row_bcast:15
    x += __builtin_amdgcn_update_dpp(0, x, 0x143, 0xC, 0xF, true); // row_bcast:31
    return __builtin_amdgcn_readlane(x, 63);
}

// ---- pass 1: rotate all q rows (T*H) and k rows (T); 4 rows per wave ----
__global__ __launch_bounds__(256) void rotate_all_kernel(
        const unsigned short* __restrict__ q, const unsigned short* __restrict__ k,
        unsigned short* __restrict__ qr, unsigned short* __restrict__ kr,
        int TH, int T) {
    int row = blockIdx.x * 16 + (threadIdx.x >> 4);
    if (row >= TH + T) return;
    int l16 = threadIdx.x & 15;
    const unsigned short* src = (row < TH) ? (q + (size_t)row * DDIM)
                                           : (k + (size_t)(row - TH) * DDIM);
    unsigned short* dst = (row < TH) ? (qr + (size_t)row * DDIM)
                                     : (kr + (size_t)(row - TH) * DDIM);
    short8 in = *(const short8*)(src + 8 * l16);
    float f[8];
    #pragma unroll
    for (int j = 0; j < 8; ++j) f[j] = bf16_to_f32((unsigned short)in[j]);
    #pragma unroll
    for (int b = 1; b <= 4; b <<= 1)
        #pragma unroll
        for (int j = 0; j < 8; ++j)
            if (!(j & b)) { float a = f[j], c = f[j | b]; f[j] = a + c; f[j | b] = a - c; }
    #pragma unroll
    for (int m = 1; m <= 8; m <<= 1) {
        bool hi = (l16 & m) != 0;
        #pragma unroll
        for (int j = 0; j < 8; ++j) {
            float o = __shfl_xor(f[j], m, 64);
            f[j] = hi ? (o - f[j]) : (f[j] + o);
        }
    }
    const float sc = 0.08838834764831845f;
    short8 out;
    #pragma unroll
    for (int j = 0; j < 8; ++j) out[j] = (short)f32_to_bf16_rne(f[j] * sc);
    *(short8*)(dst + 8 * l16) = out;
}

// ---- pass 2: fused score + select. block = 256 thr / 4 waves / 4 tokens. ----
// A = 4 tokens x 16 heads (R4-verified mapping, loaded pre-rotated from qr).
// Wave wv owns nt-subtile wv; each B-frag ds_read serves 4 tokens (4 acc chains).
__global__ __launch_bounds__(256, 3) void fused_kernel(
        const unsigned short* __restrict__ qr,  // [T*H,128] rotated bf16 bits
        const unsigned short* __restrict__ kr,  // [T,128] rotated bf16 bits
        const float* __restrict__ w,            // [T,H]
        const int* __restrict__ seq_lens, int n_seq,
        float* __restrict__ out_vals, float* __restrict__ out_idx,
        int T, int H, int K) {
    __shared__ __align__(16) unsigned short bL[2][64 * LROW];  // 34816 B
    __shared__ __align__(16) float scw[4][SCAP];               // 17536 B

    const int tid  = threadIdx.x;
    const int wv   = tid >> 6, lane = tid & 63;
    const int col  = lane & 15, kgrp = lane >> 4;
    const int srow = tid >> 4, sseg = tid & 15;   // srow 0..15

    const int tt0 = (int)blockIdx.x * 4;

    // per-lane epilogue token (token = kgrp)
    int t_l = tt0 + kgrp; if (t_l > T - 1) t_l = T - 1;
    const int ks_l = ks_of(seq_lens, n_seq, t_l);

    const int bks    = ks_of(seq_lens, n_seq, tt0);
    const int bke    = (tt0 + 4 < T) ? (tt0 + 4) : T;
    const int nchunk = (bke - bks + 63) >> 6;

    // ---- prefetch chunk 0 (rows srow, srow+16, srow+32, srow+48) ----
    short8 pre[4];
    #pragma unroll
    for (int it = 0; it < 4; ++it) {
        int gs = bks + srow + 16 * it; if (gs > T - 1) gs = T - 1;
        pre[it] = *(const short8*)(kr + (size_t)gs * DDIM + sseg * 8);
    }

    // ---- A-frags straight from qr: m-row col -> (token col>>2, head hb*4+(col&3)) ----
    short8 afragA[4][4];   // [head_group][kk]
    #pragma unroll
    for (int hb = 0; hb < 4; ++hb) {
        int tq = tt0 + (col >> 2); if (tq > T - 1) tq = T - 1;
        int hq = hb * 4 + (col & 3);
        const unsigned short* arow = qr + ((size_t)tq * H + hq) * DDIM + kgrp * 8;
        #pragma unroll
        for (int kk = 0; kk < 4; ++kk)
            afragA[hb][kk] = *(const short8*)(arow + kk * 32);
    }

    // weights for my lane's token (kgrp): all 16 heads
    float w16[16];
    {
        const float4* wp = (const float4*)(w + (size_t)t_l * H);
        #pragma unroll
        for (int i = 0; i < 4; ++i) {
            float4 v = wp[i];
            w16[4 * i] = v.x; w16[4 * i + 1] = v.y;
            w16[4 * i + 2] = v.z; w16[4 * i + 3] = v.w;
        }
    }

    // write chunk 0 to buf 0
    #pragma unroll
    for (int it = 0; it < 4; ++it)
        *(short8*)&bL[0][(srow + 16 * it) * LROW + sseg * 8] = pre[it];
    __syncthreads();

    // ---- score loop: 64-row chunks, double-buffered; wave owns nt = wv ----
    for (int c = 0; c < nchunk; ++c) {
        const int kv0 = bks + c * 64;
        if (c + 1 < nchunk) {                       // prefetch next chunk
            int kvn = kv0 + 64;
            #pragma unroll
            for (int it = 0; it < 4; ++it) {
                int gs = kvn + srow + 16 * it; if (gs > T - 1) gs = T - 1;
                pre[it] = *(const short8*)(kr + (size_t)gs * DDIM + sseg * 8);
            }
        }
        {
            const unsigned short* sb = bL[c & 1];
            float4_t a0 = {0.f,0.f,0.f,0.f}, a1 = a0, a2 = a0, a3 = a0;
            #pragma unroll
            for (int kk = 0; kk < 4; ++kk) {
                short8 bf = *(const short8*)&sb[(wv * 16 + col) * LROW + kgrp * 8 + kk * 32];
                a0 = __builtin_amdgcn_mfma_f32_16x16x32_bf16(afragA[0][kk], bf, a0, 0, 0, 0);
                a1 = __builtin_amdgcn_mfma_f32_16x16x32_bf16(afragA[1][kk], bf, a1, 0, 0, 0);
                a2 = __builtin_amdgcn_mfma_f32_16x16x32_bf16(afragA[2][kk], bf, a2, 0, 0, 0);
                a3 = __builtin_amdgcn_mfma_f32_16x16x32_bf16(afragA[3][kk], bf, a3, 0, 0, 0);
            }
            float p = 0.f;
            #pragma unroll
            for (int r = 0; r < 4; ++r) {
                float v0 = a0[r] > 0.f ? a0[r] : 0.f;
                float v1 = a1[r] > 0.f ? a1[r] : 0.f;
                float v2 = a2[r] > 0.f ? a2[r] : 0.f;
                float v3 = a3[r] > 0.f ? a3[r] : 0.f;
                p += w16[r] * v0 + w16[4 + r] * v1 + w16[8 + r] * v2 + w16[12 + r] * v3;
            }
            int s = kv0 + wv * 16 + col;
            if (s >= ks_l && s <= t_l && (tt0 + kgrp) < T)
                scw[kgrp][s - ks_l] = p;
        }
        if (c + 1 < nchunk) {                       // write other buffer (no WAR)
            #pragma unroll
            for (int it = 0; it < 4; ++it)
                *(short8*)&bL[(c + 1) & 1][(srow + 16 * it) * LROW + sseg * 8] = pre[it];
        }
        __syncthreads();
    }

    // ---- select: one wave per token (wave wv -> token tt0+wv) ----
    const int t_w = tt0 + wv;
    if (t_w >= T) return;
    const int ks_w = ks_of(seq_lens, n_seq, t_w);
    const int ke_w = t_w + 1;
    const int n    = ke_w - ks_w;

    const int nch = (n + 63) >> 6;
    uint32_t ukey[NCHT];
    #pragma unroll
    for (int c = 0; c < NCHT; ++c) {
        if (c < nch) {
            int i = c * 64 + lane;
            ukey[c] = (i < n) ? __float_as_uint(scw[wv][i]) : 0u;
        } else ukey[c] = 0u;
    }
    unsigned long long* candw = (unsigned long long*)&scw[wv][0];

    const int Keff = (n < K) ? n : K;
    uint32_t ustar = 0;
    int ttake = K;
    if (n > K) {
        uint32_t lo = 0, hi = 0x80000000u;
        for (int it = 0; it < 31; ++it) {
            uint32_t mid = (lo + hi) >> 1;
            int lc = 0;
            #pragma unroll
            for (int c = 0; c < NCHT; ++c)
                if (c < nch) lc += (ukey[c] >= mid) ? 1 : 0;
            int total = wave_reduce_add_dpp(lc);
            if (total >= K) lo = mid; else hi = mid;
        }
        ustar = lo;
        int lg = 0;
        #pragma unroll
        for (int c = 0; c < NCHT; ++c)
            if (c < nch) lg += (ukey[c] > ustar) ? 1 : 0;
        ttake = K - wave_reduce_add_dpp(lg);
    }

    // gather exactly Keff keys (ties by ascending index)
    {
        const unsigned long long ltm = (1ull << lane) - 1ull;
        int base = 0, tieBase = 0;
        const bool selAll = (n <= K);
        #pragma unroll
        for (int c = 0; c < NCHT; ++c) {
            if (c < nch) {
                int i = c * 64 + lane;
                bool inb = (i < n);
                uint32_t u = ukey[c];
                bool isGt  = inb && (selAll || u > ustar);
                bool isTie = inb && !selAll && (u == ustar);
                unsigned long long mt = __ballot(isTie);
                int tr = tieBase + (int)__popcll(mt & ltm);
                bool take = isGt || (isTie && tr < ttake);
                unsigned long long mk = __ballot(take);
                if (take) {
                    int pos = base + (int)__popcll(mk & ltm);
                    int s = ks_w + i;
                    if (pos < SORTN)
                        candw[pos] = ((((unsigned long long)u << 11) |
                                       (unsigned long long)(T - 1 - s)) + 1ull);
                }
                base    += (int)__popcll(mk);
                tieBase += (int)__popcll(mt);
            }
        }
        for (int i = Keff + lane; i < SORTN; i += 64) candw[i] = 0ull;
    }

    // register bitonic sort of 256 keys, descending; e = 4*lane + r
    unsigned long long kreg[4];
    #pragma unroll
    for (int r = 0; r < 4; ++r) kreg[r] = candw[4 * lane + r];

    #define CX(a, b, dsc) { unsigned long long _mx = (a) > (b) ? (a) : (b); \
                            unsigned long long _mn = (a) > (b) ? (b) : (a); \
                            (a) = (dsc) ? _mx : _mn; (b) = (dsc) ? _mn : _mx; }
    #pragma unroll
    for (int size = 2; size <= SORTN; size <<= 1) {
        #pragma unroll
        for (int stride = SORTN >> 1; stride >= 4; stride >>= 1) {
            if (stride > (size >> 1)) continue;
            int lmask = stride >> 2;
            #pragma unroll
            for (int r = 0; r < 4; ++r) {
                int e = 4 * lane + r;
                unsigned long long other = __shfl_xor(kreg[r], lmask, 64);
                bool desc = ((e & size) == 0);
                bool iAmLow = ((e & stride) == 0);
                bool keepMax = (iAmLow == desc);
                kreg[r] = keepMax ? (kreg[r] > other ? kreg[r] : other)
                                  : (kreg[r] < other ? kreg[r] : other);
            }
        }
        if (size >= 4) {
            bool d = (((4 * lane) & size) == 0);
            CX(kreg[0], kreg[2], d);
            CX(kreg[1], kreg[3], d);
            CX(kreg[0], kreg[1], d);
            CX(kreg[2], kreg[3], d);
        } else {
            CX(kreg[0], kreg[1], true);
            CX(kreg[2], kreg[3], false);
        }
    }
    #undef CX

    // ---- emit ----
    if (4 * lane < K) {
        float4_t v4, i4;
        #pragma unroll
        for (int r = 0; r < 4; ++r) {
            int e = 4 * lane + r;
            unsigned long long key = kreg[r];
            float v; int idx;
            if (key != 0ull) {
                unsigned long long km1 = key - 1ull;
                v = __uint_as_float((uint32_t)(km1 >> 11));
                idx = T - 1 - (int)(km1 & 0x7FFull);
            } else {
                int pidx = e - Keff;
                idx = (pidx < ks_w) ? pidx : (ke_w + (pidx - ks_w));
                v = -1e30f;
            }
            v4[r] = v; i4[r] = (float)idx;
        }
        *(float4_t*)(out_vals + (size_t)t_w * K + 4 * lane) = v4;
        *(float4_t*)(out_idx  + (size_t)t_w * K + 4 * lane) = i4;
    }
}

extern "C" void kernel_launch(void* const* d_in, const int* in_sizes, int n_in,
                              void* d_out, int out_size, void* d_ws, size_t ws_size,
                              hipStream_t stream) {
    const unsigned short* q = (const unsigned short*)d_in[0];
    const unsigned short* k = (const unsigned short*)d_in[1];
    const float* w          = (const float*)d_in[2];
    const int* seq_lens     = (const int*)d_in[3];
    const int n_seq = in_sizes[3];
    const int T = in_sizes[1] / DDIM;
    const int H = in_sizes[2] / T;
    const int K = out_size / (2 * T);

    // ws layout: qr bf16[T*H*128] | kr bf16[T*128]
    unsigned short* qr = (unsigned short*)d_ws;
    unsigned short* kr = qr + (size_t)T * H * DDIM;

    float* out_vals = (float*)d_out;
    float* out_idx  = out_vals + (size_t)T * K;

    const int TH = T * H;
    rotate_all_kernel<<<dim3((TH + T + 15) / 16), dim3(256), 0, stream>>>(q, k, qr, kr, TH, T);
    fused_kernel<<<dim3((T + 3) / 4), dim3(256), 0, stream>>>(
        qr, kr, w, seq_lens, n_seq, out_vals, out_idx, T, H, K);
}

// Round 16
// 104.332 us; speedup vs baseline: 1.2320x; 1.0216x over previous
//
#include <hip/hip_runtime.h>
#include <hip/hip_bf16.h>
#include <stdint.h>

typedef __attribute__((ext_vector_type(8))) short short8;
typedef __attribute__((ext_vector_type(4))) float float4_t;

#define DDIM 128
#define SORTN 256
#define LROW 136     // LDS B row pitch in shorts (272 B): 2-way (free) read aliasing
#define SCAP 1088    // per-token score capacity (floats); >= 2048 B for cand alias
#define NCHT 17      // selection chunks of 64 (covers n <= 1088)

__device__ inline unsigned short f32_to_bf16_rne(float f) {
    uint32_t u = __float_as_uint(f);
    return (unsigned short)((u + 0x7FFFu + ((u >> 16) & 1u)) >> 16);
}
__device__ inline float bf16_to_f32(unsigned short h) {
    return __uint_as_float(((uint32_t)h) << 16);
}
__device__ inline int ks_of(const int* seq_lens, int n_seq, int t) {
    int off = 0, r = 0;
    for (int i = 0; i < n_seq; ++i) {
        int nx = off + seq_lens[i];
        if (t < nx) { r = off; break; }
        off = nx;
    }
    return r;
}

// wave64 sum via DPP (VALU pipe; no DS contention). Result uniform.
__device__ inline int wave_reduce_add_dpp(int x) {
    x += __builtin_amdgcn_update_dpp(0, x, 0x111, 0xF, 0xF, true); // row_shr:1
    x += __builtin_amdgcn_update_dpp(0, x, 0x112, 0xF, 0xF, true); // row_shr:2
    x += __builtin_amdgcn_update_dpp(0, x, 0x114, 0xF, 0xF, true); // row_shr:4
    x += __builtin_amdgcn_update_dpp(0, x, 0x118, 0xF, 0xF, true); // row_shr:8
    x += __builtin_amdgcn_update_dpp(0, x, 0x142, 0xA, 0xF, true); // row_bcast:15
    x += __builtin_amdgcn_update_dpp(0, x, 0x143, 0xC, 0xF, true); // row_bcast:31
    return __builtin_amdgcn_readlane(x, 63);
}

// ---- pass 1: rotate k rows ----
__global__ __launch_bounds__(256) void rotate_k_kernel(
        const unsigned short* __restrict__ k, unsigned short* __restrict__ kr, int T) {
    int row = blockIdx.x * 16 + (threadIdx.x >> 4);
    if (row >= T) return;
    int l16 = threadIdx.x & 15;
    short8 in = *(const short8*)(k + (size_t)row * DDIM + 8 * l16);
    float f[8];
    #pragma unroll
    for (int j = 0; j < 8; ++j) f[j] = bf16_to_f32((unsigned short)in[j]);
    #pragma unroll
    for (int b = 1; b <= 4; b <<= 1)
        #pragma unroll
        for (int j = 0; j < 8; ++j)
            if (!(j & b)) { float a = f[j], c = f[j | b]; f[j] = a + c; f[j | b] = a - c; }
    #pragma unroll
    for (int m = 1; m <= 8; m <<= 1) {
        bool hi = (l16 & m) != 0;
        #pragma unroll
        for (int j = 0; j < 8; ++j) {
            float o = __shfl_xor(f[j], m, 64);
            f[j] = hi ? (o - f[j]) : (f[j] + o);
        }
    }
    const float sc = 0.08838834764831845f;
    short8 out;
    #pragma unroll
    for (int j = 0; j < 8; ++j) out[j] = (short)f32_to_bf16_rne(f[j] * sc);
    *(short8*)(kr + (size_t)row * DDIM + 8 * l16) = out;
}

// ---- pass 2: fused score + select. block = 4 tokens x 2 waves each. ----
// 64-row double-buffered B chunks: one barrier per chunk; LDS write overlaps compute.
__global__ __launch_bounds__(512, 4) void fused_kernel(
        const unsigned short* __restrict__ q,   // [T,H,128] bf16 bits (unrotated)
        const unsigned short* __restrict__ kr,  // [T,128] rotated bf16 bits
        const float* __restrict__ w,            // [T,H]
        const int* __restrict__ seq_lens, int n_seq,
        float* __restrict__ out_vals, float* __restrict__ out_idx,
        int T, int H, int K, int Tt) {
    __shared__ __align__(16) unsigned short bL[2][64 * LROW];  // 34816 B
    __shared__ __align__(16) float scw[4][SCAP];               // 17408 B

    const int tid  = threadIdx.x;
    const int wv   = tid >> 6, lane = tid & 63;
    const int tok  = wv & 3, half = wv >> 2;
    const int col  = lane & 15, kgrp = lane >> 4;
    const int srow = tid >> 4, sseg = tid & 15;   // srow 0..31

    // shallow/deep interleave for makespan balance
    const int m     = blockIdx.x;
    const int ttile = (m & 1) ? (Tt - 1 - (m >> 1)) : (m >> 1);
    const int tt0   = ttile * 4;
    const int t_w   = tt0 + tok;
    const bool wvalid = (t_w < T);
    const int t_c  = wvalid ? t_w : T - 1;
    const int ks_w = ks_of(seq_lens, n_seq, t_c);
    const int ke_w = t_c + 1;
    const int n    = ke_w - ks_w;

    const int bks    = ks_of(seq_lens, n_seq, tt0);
    const int bke    = (tt0 + 4 < T) ? (tt0 + 4) : T;
    const int nchunk = (bke - bks + 63) >> 6;

    // ---- prefetch chunk 0 (rows srow, srow+32) ----
    short8 pre[2];
    #pragma unroll
    for (int it = 0; it < 2; ++it) {
        int gs = bks + srow + 32 * it; if (gs > T - 1) gs = T - 1;
        pre[it] = *(const short8*)(kr + (size_t)gs * DDIM + sseg * 8);
    }

    // ---- rotate q[t_c] in registers (16 head-rows; verified FWHT) ----
    float f[4][8];
    const unsigned short* qrow = q + ((size_t)t_c * H + col) * DDIM + kgrp * 8;
    #pragma unroll
    for (int kk = 0; kk < 4; ++kk) {
        short8 v = *(const short8*)(qrow + kk * 32);
        #pragma unroll
        for (int j = 0; j < 8; ++j) f[kk][j] = bf16_to_f32((unsigned short)v[j]);
    }
    #pragma unroll
    for (int b = 1; b <= 4; b <<= 1)
        #pragma unroll
        for (int kk = 0; kk < 4; ++kk)
            #pragma unroll
            for (int j = 0; j < 8; ++j)
                if (!(j & b)) { float a = f[kk][j], c = f[kk][j | b];
                                f[kk][j] = a + c; f[kk][j | b] = a - c; }
    #pragma unroll
    for (int kk = 0; kk < 4; ++kk)
        #pragma unroll
        for (int j = 0; j < 8; ++j) {
            float o = __shfl_xor(f[kk][j], 16, 64);
            f[kk][j] = (kgrp & 1) ? (o - f[kk][j]) : (f[kk][j] + o);
        }
    #pragma unroll
    for (int kk = 0; kk < 4; ++kk)
        #pragma unroll
        for (int j = 0; j < 8; ++j) {
            float o = __shfl_xor(f[kk][j], 32, 64);
            f[kk][j] = (kgrp & 2) ? (o - f[kk][j]) : (f[kk][j] + o);
        }
    #pragma unroll
    for (int j = 0; j < 8; ++j) {
        { float a = f[0][j], c = f[1][j]; f[0][j] = a + c; f[1][j] = a - c; }
        { float a = f[2][j], c = f[3][j]; f[2][j] = a + c; f[3][j] = a - c; }
        { float a = f[0][j], c = f[2][j]; f[0][j] = a + c; f[2][j] = a - c; }
        { float a = f[1][j], c = f[3][j]; f[1][j] = a + c; f[3][j] = a - c; }
    }
    short8 afrag[4];
    const float scl = 0.08838834764831845f;
    #pragma unroll
    for (int kk = 0; kk < 4; ++kk)
        #pragma unroll
        for (int j = 0; j < 8; ++j)
            afrag[kk][j] = (short)f32_to_bf16_rne(f[kk][j] * scl);

    float w4[4];
    #pragma unroll
    for (int r = 0; r < 4; ++r) w4[r] = w[(size_t)t_c * H + kgrp * 4 + r];

    // write chunk 0 to buf 0
    #pragma unroll
    for (int it = 0; it < 2; ++it)
        *(short8*)&bL[0][(srow + 32 * it) * LROW + sseg * 8] = pre[it];
    __syncthreads();

    // ---- score loop: 64-row chunks; wave computes nt = half*2 + {0,1} ----
    for (int c = 0; c < nchunk; ++c) {
        const int kv0 = bks + c * 64;
        if (c + 1 < nchunk) {                       // prefetch next chunk
            int kvn = kv0 + 64;
            #pragma unroll
            for (int it = 0; it < 2; ++it) {
                int gs = kvn + srow + 32 * it; if (gs > T - 1) gs = T - 1;
                pre[it] = *(const short8*)(kr + (size_t)gs * DDIM + sseg * 8);
            }
        }
        const unsigned short* sb = bL[c & 1];
        #pragma unroll
        for (int nth = 0; nth < 2; ++nth) {
            const int nt = half * 2 + nth;
            float4_t acc = {0.f, 0.f, 0.f, 0.f};
            #pragma unroll
            for (int kk = 0; kk < 4; ++kk) {
                short8 bf = *(const short8*)&sb[(nt * 16 + col) * LROW + kgrp * 8 + kk * 32];
                acc = __builtin_amdgcn_mfma_f32_16x16x32_bf16(afrag[kk], bf, acc, 0, 0, 0);
            }
            float p = 0.f;
            #pragma unroll
            for (int r = 0; r < 4; ++r) {
                float v = acc[r];
                v = v > 0.f ? v : 0.f;
                p += w4[r] * v;
            }
            p += __shfl_xor(p, 16, 64);
            p += __shfl_xor(p, 32, 64);
            int s = kv0 + nt * 16 + col;
            if (wvalid && lane < 16 && s >= ks_w && s <= t_w)
                scw[tok][s - ks_w] = p;
        }
        if (c + 1 < nchunk) {                       // write to other buffer (no WAR)
            #pragma unroll
            for (int it = 0; it < 2; ++it)
                *(short8*)&bL[(c + 1) & 1][(srow + 32 * it) * LROW + sseg * 8] = pre[it];
        }
        __syncthreads();
    }

    // waves 4..7 done (scw visible after final barrier)
    if (half == 1 || !wvalid) return;

    // ---- select (one wave per token) ----
    const int nch = (n + 63) >> 6;
    uint32_t ukey[NCHT];
    #pragma unroll
    for (int c = 0; c < NCHT; ++c) {
        if (c < nch) {
            int i = c * 64 + lane;
            ukey[c] = (i < n) ? __float_as_uint(scw[tok][i]) : 0u;
        } else ukey[c] = 0u;
    }
    unsigned long long* candw = (unsigned long long*)&scw[tok][0];

    const int Keff = (n < K) ? n : K;
    uint32_t ustar = 0;
    int ttake = K;
    if (n > K) {
        uint32_t lo = 0, hi = 0x80000000u;
        for (int it = 0; it < 31; ++it) {
            uint32_t mid = (lo + hi) >> 1;
            int lc = 0;
            #pragma unroll
            for (int c = 0; c < NCHT; ++c)
                if (c < nch) lc += (ukey[c] >= mid) ? 1 : 0;
            int total = wave_reduce_add_dpp(lc);
            if (total >= K) lo = mid; else hi = mid;
        }
        ustar = lo;
        int lg = 0;
        #pragma unroll
        for (int c = 0; c < NCHT; ++c)
            if (c < nch) lg += (ukey[c] > ustar) ? 1 : 0;
        ttake = K - wave_reduce_add_dpp(lg);
    }

    // gather exactly Keff keys (ties by ascending index)
    {
        const unsigned long long ltm = (1ull << lane) - 1ull;
        int base = 0, tieBase = 0;
        const bool selAll = (n <= K);
        #pragma unroll
        for (int c = 0; c < NCHT; ++c) {
            if (c < nch) {
                int i = c * 64 + lane;
                bool inb = (i < n);
                uint32_t u = ukey[c];
                bool isGt  = inb && (selAll || u > ustar);
                bool isTie = inb && !selAll && (u == ustar);
                unsigned long long mt = __ballot(isTie);
                int tr = tieBase + (int)__popcll(mt & ltm);
                bool take = isGt || (isTie && tr < ttake);
                unsigned long long mk = __ballot(take);
                if (take) {
                    int pos = base + (int)__popcll(mk & ltm);
                    int s = ks_w + i;
                    if (pos < SORTN)
                        candw[pos] = ((((unsigned long long)u << 11) |
                                       (unsigned long long)(T - 1 - s)) + 1ull);
                }
                base    += (int)__popcll(mk);
                tieBase += (int)__popcll(mt);
            }
        }
        for (int i = Keff + lane; i < SORTN; i += 64) candw[i] = 0ull;
    }

    // register bitonic sort of 256 keys, descending; e = 4*lane + r
    unsigned long long kreg[4];
    #pragma unroll
    for (int r = 0; r < 4; ++r) kreg[r] = candw[4 * lane + r];

    #define CX(a, b, dsc) { unsigned long long _mx = (a) > (b) ? (a) : (b); \
                            unsigned long long _mn = (a) > (b) ? (b) : (a); \
                            (a) = (dsc) ? _mx : _mn; (b) = (dsc) ? _mn : _mx; }
    #pragma unroll
    for (int size = 2; size <= SORTN; size <<= 1) {
        #pragma unroll
        for (int stride = SORTN >> 1; stride >= 4; stride >>= 1) {
            if (stride > (size >> 1)) continue;
            int lmask = stride >> 2;
            #pragma unroll
            for (int r = 0; r < 4; ++r) {
                int e = 4 * lane + r;
                unsigned long long other = __shfl_xor(kreg[r], lmask, 64);
                bool desc = ((e & size) == 0);
                bool iAmLow = ((e & stride) == 0);
                bool keepMax = (iAmLow == desc);
                kreg[r] = keepMax ? (kreg[r] > other ? kreg[r] : other)
                                  : (kreg[r] < other ? kreg[r] : other);
            }
        }
        if (size >= 4) {
            bool d = (((4 * lane) & size) == 0);
            CX(kreg[0], kreg[2], d);
            CX(kreg[1], kreg[3], d);
            CX(kreg[0], kreg[1], d);
            CX(kreg[2], kreg[3], d);
        } else {
            CX(kreg[0], kreg[1], true);
            CX(kreg[2], kreg[3], false);
        }
    }
    #undef CX

    // ---- emit ----
    if (4 * lane < K) {
        float4_t v4, i4;
        #pragma unroll
        for (int r = 0; r < 4; ++r) {
            int e = 4 * lane + r;
            unsigned long long key = kreg[r];
            float v; int idx;
            if (key != 0ull) {
                unsigned long long km1 = key - 1ull;
                v = __uint_as_float((uint32_t)(km1 >> 11));
                idx = T - 1 - (int)(km1 & 0x7FFull);
            } else {
                int pidx = e - Keff;
                idx = (pidx < ks_w) ? pidx : (ke_w + (pidx - ks_w));
                v = -1e30f;
            }
            v4[r] = v; i4[r] = (float)idx;
        }
        *(float4_t*)(out_vals + (size_t)t_w * K + 4 * lane) = v4;
        *(float4_t*)(out_idx  + (size_t)t_w * K + 4 * lane) = i4;
    }
}

extern "C" void kernel_launch(void* const* d_in, const int* in_sizes, int n_in,
                              void* d_out, int out_size, void* d_ws, size_t ws_size,
                              hipStream_t stream) {
    const unsigned short* q = (const unsigned short*)d_in[0];
    const unsigned short* k = (const unsigned short*)d_in[1];
    const float* w          = (const float*)d_in[2];
    const int* seq_lens     = (const int*)d_in[3];
    const int n_seq = in_sizes[3];
    const int T = in_sizes[1] / DDIM;
    const int H = in_sizes[2] / T;
    const int K = out_size / (2 * T);

    unsigned short* kr = (unsigned short*)d_ws;   // [T,128] rotated k (512 KB)
    float* out_vals = (float*)d_out;
    float* out_idx  = out_vals + (size_t)T * K;

    rotate_k_kernel<<<dim3((T + 15) / 16), dim3(256), 0, stream>>>(k, kr, T);
    const int Tt = (T + 3) / 4;
    fused_kernel<<<dim3(Tt), dim3(512), 0, stream>>>(
        q, kr, w, seq_lens, n_seq, out_vals, out_idx, T, H, K, Tt);
}